// Round 10
// baseline (201.677 us; speedup 1.0000x reference)
//
#include <hip/hip_runtime.h>
#include <math.h>

#define B_ 16
#define N_ 4096
#define K_ 16
#define ALPHA_ 1.05f

#define WAVES 8             // waves per block, one j-chunk each
#define CHUNKW (N_ / WAVES) // 512 j's per wave
#define TJ 256              // j-tile staged in LDS per wave
#define PTS 64              // points per block (one per lane)
#define BLK 512             // 8 waves
#define SENT_F 60000.0f     // sentinel > any real sq-dist (~300); f16-representable

typedef __fp16 h2 __attribute__((ext_vector_type(2)));

struct H2x4 { h2 v[4]; };   // view of one float4 = 8 fp16 = 4 h2 pairs

// ---------------------------------------------------------------------------
// Packed f16 ops (VOP3P) via inline asm.
// ---------------------------------------------------------------------------
__device__ __forceinline__ h2 h2min(h2 a, h2 b) {
    unsigned int ua = __builtin_bit_cast(unsigned int, a);
    unsigned int ub = __builtin_bit_cast(unsigned int, b);
    unsigned int r;
    asm("v_pk_min_f16 %0, %1, %2" : "=v"(r) : "v"(ua), "v"(ub));
    return __builtin_bit_cast(h2, r);
}
__device__ __forceinline__ h2 h2max(h2 a, h2 b) {
    unsigned int ua = __builtin_bit_cast(unsigned int, a);
    unsigned int ub = __builtin_bit_cast(unsigned int, b);
    unsigned int r;
    asm("v_pk_max_f16 %0, %1, %2" : "=v"(r) : "v"(ua), "v"(ub));
    return __builtin_bit_cast(h2, r);
}
__device__ __forceinline__ h2 h2add(h2 a, h2 b) {
    unsigned int ua = __builtin_bit_cast(unsigned int, a);
    unsigned int ub = __builtin_bit_cast(unsigned int, b);
    unsigned int r;
    asm("v_pk_add_f16 %0, %1, %2" : "=v"(r) : "v"(ua), "v"(ub));
    return __builtin_bit_cast(h2, r);
}
__device__ __forceinline__ h2 h2mul(h2 a, h2 b) {
    unsigned int ua = __builtin_bit_cast(unsigned int, a);
    unsigned int ub = __builtin_bit_cast(unsigned int, b);
    unsigned int r;
    asm("v_pk_mul_f16 %0, %1, %2" : "=v"(r) : "v"(ua), "v"(ub));
    return __builtin_bit_cast(h2, r);
}
__device__ __forceinline__ h2 h2fma(h2 a, h2 b, h2 c) {
    unsigned int ua = __builtin_bit_cast(unsigned int, a);
    unsigned int ub = __builtin_bit_cast(unsigned int, b);
    unsigned int uc = __builtin_bit_cast(unsigned int, c);
    unsigned int r;
    asm("v_pk_fma_f16 %0, %1, %2, %3" : "=v"(r) : "v"(ua), "v"(ub), "v"(uc));
    return __builtin_bit_cast(h2, r);
}

// ---------------------------------------------------------------------------
// Batcher odd-even merge sort, n=16, ascending: 63 CE, 2 streams per instr.
// ---------------------------------------------------------------------------
__device__ __forceinline__ void oems_sort16h(h2 v[16]) {
#pragma unroll
    for (int p = 1; p < 16; p <<= 1) {
#pragma unroll
        for (int k = p; k >= 1; k >>= 1) {
#pragma unroll
            for (int j = k & (p - 1); j + k < 16; j += 2 * k) {
#pragma unroll
                for (int i = 0; i < k; ++i) {
                    if (i + j + k < 16 &&
                        ((i + j) / (2 * p)) == ((i + j + k) / (2 * p))) {
                        const h2 a = v[i + j], b = v[i + j + k];
                        v[i + j]     = h2min(a, b);
                        v[i + j + k] = h2max(a, b);
                    }
                }
            }
        }
    }
}

// knn (sorted asc, packed) := lowest 16 of {knn, c} per half; c sorted asc.
__device__ __forceinline__ void merge16h(h2 knn[16], const h2 c[16]) {
#pragma unroll
    for (int i = 0; i < 16; ++i) knn[i] = h2min(knn[i], c[15 - i]);
#pragma unroll
    for (int j = 8; j > 0; j >>= 1) {
#pragma unroll
        for (int i = 0; i < 16; ++i) {
            const int l = i ^ j;
            if (l > i) {
                const h2 a = knn[i], b = knn[l];
                knn[i] = h2min(a, b);
                knn[l] = h2max(a, b);
            }
        }
    }
}

// f32 merge for the once-per-wave lo/hi combine (both sorted asc).
__device__ __forceinline__ void merge16f(float knn[16], const float c[16]) {
#pragma unroll
    for (int i = 0; i < 16; ++i) knn[i] = fminf(knn[i], c[15 - i]);
#pragma unroll
    for (int j = 8; j > 0; j >>= 1) {
#pragma unroll
        for (int i = 0; i < 16; ++i) {
            const int l = i ^ j;
            if (l > i) {
                const float a = knn[i], b = knn[l];
                knn[i] = fminf(a, b);
                knn[l] = fmaxf(a, b);
            }
        }
    }
}

// ---------------------------------------------------------------------------
// Process one 256-j f16-SoA tile (coords stored NEGATED): 8 batches of 32 j.
// ---------------------------------------------------------------------------
template <bool HAS_SELF>
__device__ __forceinline__ void process_tile(const float4* __restrict__ xs4,
                                             const float4* __restrict__ ys4,
                                             const float4* __restrict__ zs4,
                                             int jg0, int i,
                                             h2 qx, h2 qy, h2 qz,
                                             h2 knn[16]) {
#pragma unroll 1
    for (int bb = 0; bb < TJ / 32; ++bb) {
        h2 c[16];
#pragma unroll
        for (int r = 0; r < 4; ++r) {
            const H2x4 hx = __builtin_bit_cast(H2x4, xs4[bb * 4 + r]); // b128 broadcast
            const H2x4 hy = __builtin_bit_cast(H2x4, ys4[bb * 4 + r]);
            const H2x4 hz = __builtin_bit_cast(H2x4, zs4[bb * 4 + r]);
#pragma unroll
            for (int t = 0; t < 4; ++t) {
                const h2 dx = h2add(qx, hx.v[t]);
                const h2 dy = h2add(qy, hy.v[t]);
                const h2 dz = h2add(qz, hz.v[t]);
                h2 d = h2mul(dx, dx);
                d = h2fma(dy, dy, d);
                d = h2fma(dz, dz, d);
                if (HAS_SELF) {
                    const int j0 = jg0 + bb * 32 + r * 8 + 2 * t;
                    if (j0 == i)     d.x = (__fp16)SENT_F;
                    if (j0 + 1 == i) d.y = (__fp16)SENT_F;
                }
                c[r * 4 + t] = d;
            }
        }
        oems_sort16h(c);
        merge16h(knn, c);
    }
}

// ---------------------------------------------------------------------------
// Block reduction (512 threads = 8 waves)
// ---------------------------------------------------------------------------
__device__ __forceinline__ float block_reduce_sum_512(float v, float* sbuf) {
    const int lane = threadIdx.x & 63;
    const int w    = threadIdx.x >> 6;
#pragma unroll
    for (int o = 32; o > 0; o >>= 1) v += __shfl_down(v, o, 64);
    __syncthreads();
    if (lane == 0) sbuf[w] = v;
    __syncthreads();
    float s = 0.0f;
#pragma unroll
    for (int t = 0; t < WAVES; ++t) s += sbuf[t];
    return s;
}

// ---------------------------------------------------------------------------
// Fused kernel: kNN mean distances + (last block per batch) stats + penalty
// + (last batch finisher) final scalar. Block = 512 threads = 8 waves.
// __launch_bounds__(512, 6): 6 waves/EU -> 3 blocks/CU = 24 waves/CU,
// VGPR cap ~85 (main loop needs ~55; round-9's (512,8) cap of 32 spilled).
// ctrl layout: ctrl[0..15] per-batch block counters, ctrl[16] batch-done
// counter, ctrl[17] (as float) penalty accumulator. Zeroed per launch.
// ---------------------------------------------------------------------------
__global__ __launch_bounds__(BLK, 6) void knn_fused(const float* __restrict__ pcs,
                                                    float* __restrict__ knn_d,
                                                    int* __restrict__ ctrl,
                                                    float* __restrict__ out) {
    __shared__ float4 s[WAVES][3][TJ / 8];       // f16 SoA x/y/z, 12 KB
    __shared__ __fp16 lst[WAVES][PTS][K_ + 1];   // 17 KB (+1: sentinel/pad)
    __shared__ float  sbuf[WAVES];
    __shared__ int    sflag;

    const int b    = blockIdx.x >> 6;            // 64 blocks per batch
    const int grp  = blockIdx.x & 63;
    const int i0   = grp * PTS;
    const int lane = threadIdx.x & 63;
    const int w    = threadIdx.x >> 6;           // 0..7

    const float* __restrict__ src = pcs + (size_t)b * N_ * 3;

    const int i  = i0 + lane;
    const __fp16 qxh = (__fp16)src[3 * i + 0];   // RTN, same grid as candidates
    const __fp16 qyh = (__fp16)src[3 * i + 1];
    const __fp16 qzh = (__fp16)src[3 * i + 2];
    const h2 qx = {qxh, qxh}, qy = {qyh, qyh}, qz = {qzh, qzh};

    const h2 sent = {(__fp16)SENT_F, (__fp16)SENT_F};
    h2 knn[K_];
#pragma unroll
    for (int t = 0; t < K_; ++t) knn[t] = sent;

    const int jbase = w * CHUNKW;
    h2* sxw = (h2*)&s[w][0][0];
    h2* syw = (h2*)&s[w][1][0];
    h2* szw = (h2*)&s[w][2][0];

#pragma unroll 1
    for (int t0 = 0; t0 < CHUNKW; t0 += TJ) {
        // ---- stage: lane l loads 4 points (3 float4), converts NEGATED (RTN)
        //      to f16, writes paired h2 SoA into this wave's quadrant.
        const float4* __restrict__ g4 =
            (const float4*)(src + (size_t)(jbase + t0) * 3);
        const float4 f0 = g4[3 * lane + 0];
        const float4 f1 = g4[3 * lane + 1];
        const float4 f2 = g4[3 * lane + 2];
        sxw[2 * lane + 0] = h2{(__fp16)(-f0.x), (__fp16)(-f0.w)};
        sxw[2 * lane + 1] = h2{(__fp16)(-f1.z), (__fp16)(-f2.y)};
        syw[2 * lane + 0] = h2{(__fp16)(-f0.y), (__fp16)(-f1.x)};
        syw[2 * lane + 1] = h2{(__fp16)(-f1.w), (__fp16)(-f2.z)};
        szw[2 * lane + 0] = h2{(__fp16)(-f0.z), (__fp16)(-f1.y)};
        szw[2 * lane + 1] = h2{(__fp16)(-f2.x), (__fp16)(-f2.w)};
        // wave-private quadrant; lanes lockstep within the wave, compiler
        // inserts lgkmcnt waits for the write->read dependence. No barrier.

        const int jg0 = jbase + t0;
        if ((i0 >> 8) == (jg0 >> 8)) {
            process_tile<true >(&s[w][0][0], &s[w][1][0], &s[w][2][0],
                                jg0, i, qx, qy, qz, knn);
        } else {
            process_tile<false>(&s[w][0][0], &s[w][1][0], &s[w][2][0],
                                jg0, i, qx, qy, qz, knn);
        }
    }

    // ---- combine the two packed streams (lo/hi), once per wave
    float lo[K_], hi[K_];
#pragma unroll
    for (int t = 0; t < K_; ++t) { lo[t] = (float)knn[t].x; hi[t] = (float)knn[t].y; }
    merge16f(lo, hi);   // lowest 16 of 32, sorted asc (values are exact f16)

#pragma unroll
    for (int q = 0; q < K_; ++q) lst[w][lane][q] = (__fp16)lo[q];
    lst[w][lane][K_] = (__fp16)SENT_F;
    __syncthreads();

    // ---- 8-way merge of sorted lists, one thread per point
    if (threadIdx.x < PTS) {
        const int l = threadIdx.x;
        int p0 = 0, p1 = 0, p2 = 0, p3 = 0, p4 = 0, p5 = 0, p6 = 0, p7 = 0;
        float m0 = (float)lst[0][l][0], m1 = (float)lst[1][l][0];
        float m2 = (float)lst[2][l][0], m3 = (float)lst[3][l][0];
        float m4 = (float)lst[4][l][0], m5 = (float)lst[5][l][0];
        float m6 = (float)lst[6][l][0], m7 = (float)lst[7][l][0];
        float sm = 0.0f;
#pragma unroll
        for (int st = 0; st < K_; ++st) {
            const float m = fminf(fminf(fminf(m0, m1), fminf(m2, m3)),
                                  fminf(fminf(m4, m5), fminf(m6, m7)));
            sm += m;
            if (m0 == m)      { m0 = (float)lst[0][l][++p0]; }
            else if (m1 == m) { m1 = (float)lst[1][l][++p1]; }
            else if (m2 == m) { m2 = (float)lst[2][l][++p2]; }
            else if (m3 == m) { m3 = (float)lst[3][l][++p3]; }
            else if (m4 == m) { m4 = (float)lst[4][l][++p4]; }
            else if (m5 == m) { m5 = (float)lst[5][l][++p5]; }
            else if (m6 == m) { m6 = (float)lst[6][l][++p6]; }
            else              { m7 = (float)lst[7][l][++p7]; }
        }
        knn_d[(size_t)b * N_ + i0 + l] = sm * (1.0f / (float)K_);
    }

    // ---- last-block-done: the 64th block of this batch computes the stats
    __threadfence();
    __syncthreads();
    if (threadIdx.x == 0) {
        const int old = atomicAdd(&ctrl[b], 1);
        sflag = (old == 63);
    }
    __syncthreads();

    if (sflag) {
        const float* __restrict__ xrow = knn_d + (size_t)b * N_;
        float v[8];
        float ssum = 0.0f;
#pragma unroll
        for (int t = 0; t < 8; ++t) {
            v[t] = __hip_atomic_load(&xrow[threadIdx.x + t * BLK],
                                     __ATOMIC_RELAXED, __HIP_MEMORY_SCOPE_AGENT);
            ssum += v[t];
        }
        const float mu = block_reduce_sum_512(ssum, sbuf) * (1.0f / (float)N_);

        float vs = 0.0f;
#pragma unroll
        for (int t = 0; t < 8; ++t) {
            const float d = v[t] - mu;
            vs += d * d;
        }
        const float var    = block_reduce_sum_512(vs, sbuf) * (1.0f / (float)N_);
        const float thresh = mu + ALPHA_ * sqrtf(var);

        float p = 0.0f;
#pragma unroll
        for (int t = 0; t < 8; ++t) {
            if (v[t] > thresh) p += v[t];
        }
        const float psum = block_reduce_sum_512(p, sbuf);

        if (threadIdx.x == 0) {
            float* acc = (float*)(ctrl + 17);
            atomicAdd(acc, psum);
            __threadfence();
            const int done = atomicAdd(&ctrl[16], 1);
            if (done == 15) {
                const float tot = atomicAdd(acc, 0.0f);   // read full sum
                out[0] = tot * (1.0f / (float)(B_ * N_));
            }
        }
    }
}

extern "C" void kernel_launch(void* const* d_in, const int* in_sizes, int n_in,
                              void* d_out, int out_size, void* d_ws, size_t ws_size,
                              hipStream_t stream) {
    const float* pcs = (const float*)d_in[0];
    float* out = (float*)d_out;

    float* knn_d = (float*)d_ws;                          // B*N floats = 256 KB
    int*   ctrl  = (int*)((char*)d_ws + B_ * N_ * sizeof(float));

    (void)hipMemsetAsync(ctrl, 0, 128, stream);           // counters + accumulator
    knn_fused<<<B_ * (N_ / PTS), BLK, 0, stream>>>(pcs, knn_d, ctrl, out);
}

// Round 11
// 135.262 us; speedup vs baseline: 1.4910x; 1.4910x over previous
//
#include <hip/hip_runtime.h>
#include <math.h>

#define B_ 16
#define N_ 4096
#define K_ 16
#define ALPHA_ 1.05f

#define JSPLIT 4            // j-chunks per point (one wave each)
#define CHUNK (N_ / JSPLIT) // 1024 j's per wave
#define TJ 256              // j-tile staged in LDS per wave
#define PTS 64              // points per block (one per lane)
#define BLK 256             // 4 waves
#define SENT_F 60000.0f     // sentinel > any real sq-dist (~300); f16-representable

typedef __fp16 h2 __attribute__((ext_vector_type(2)));

struct H2x4 { h2 v[4]; };   // view of one float4 = 8 fp16 = 4 h2 pairs

// ---------------------------------------------------------------------------
// Packed f16 ops (VOP3P) via inline asm.
// ---------------------------------------------------------------------------
__device__ __forceinline__ h2 h2min(h2 a, h2 b) {
    unsigned int ua = __builtin_bit_cast(unsigned int, a);
    unsigned int ub = __builtin_bit_cast(unsigned int, b);
    unsigned int r;
    asm("v_pk_min_f16 %0, %1, %2" : "=v"(r) : "v"(ua), "v"(ub));
    return __builtin_bit_cast(h2, r);
}
__device__ __forceinline__ h2 h2max(h2 a, h2 b) {
    unsigned int ua = __builtin_bit_cast(unsigned int, a);
    unsigned int ub = __builtin_bit_cast(unsigned int, b);
    unsigned int r;
    asm("v_pk_max_f16 %0, %1, %2" : "=v"(r) : "v"(ua), "v"(ub));
    return __builtin_bit_cast(h2, r);
}
__device__ __forceinline__ h2 h2add(h2 a, h2 b) {
    unsigned int ua = __builtin_bit_cast(unsigned int, a);
    unsigned int ub = __builtin_bit_cast(unsigned int, b);
    unsigned int r;
    asm("v_pk_add_f16 %0, %1, %2" : "=v"(r) : "v"(ua), "v"(ub));
    return __builtin_bit_cast(h2, r);
}
__device__ __forceinline__ h2 h2mul(h2 a, h2 b) {
    unsigned int ua = __builtin_bit_cast(unsigned int, a);
    unsigned int ub = __builtin_bit_cast(unsigned int, b);
    unsigned int r;
    asm("v_pk_mul_f16 %0, %1, %2" : "=v"(r) : "v"(ua), "v"(ub));
    return __builtin_bit_cast(h2, r);
}
__device__ __forceinline__ h2 h2fma(h2 a, h2 b, h2 c) {
    unsigned int ua = __builtin_bit_cast(unsigned int, a);
    unsigned int ub = __builtin_bit_cast(unsigned int, b);
    unsigned int uc = __builtin_bit_cast(unsigned int, c);
    unsigned int r;
    asm("v_pk_fma_f16 %0, %1, %2, %3" : "=v"(r) : "v"(ua), "v"(ub), "v"(uc));
    return __builtin_bit_cast(h2, r);
}

// ---------------------------------------------------------------------------
// Batcher odd-even merge sort, n=16, ascending: 63 CE, 2 streams per instr.
// ---------------------------------------------------------------------------
__device__ __forceinline__ void oems_sort16h(h2 v[16]) {
#pragma unroll
    for (int p = 1; p < 16; p <<= 1) {
#pragma unroll
        for (int k = p; k >= 1; k >>= 1) {
#pragma unroll
            for (int j = k & (p - 1); j + k < 16; j += 2 * k) {
#pragma unroll
                for (int i = 0; i < k; ++i) {
                    if (i + j + k < 16 &&
                        ((i + j) / (2 * p)) == ((i + j + k) / (2 * p))) {
                        const h2 a = v[i + j], b = v[i + j + k];
                        v[i + j]     = h2min(a, b);
                        v[i + j + k] = h2max(a, b);
                    }
                }
            }
        }
    }
}

// knn (sorted asc, packed) := lowest 16 of {knn, c} per half; c sorted asc.
__device__ __forceinline__ void merge16h(h2 knn[16], const h2 c[16]) {
#pragma unroll
    for (int i = 0; i < 16; ++i) knn[i] = h2min(knn[i], c[15 - i]);
#pragma unroll
    for (int j = 8; j > 0; j >>= 1) {
#pragma unroll
        for (int i = 0; i < 16; ++i) {
            const int l = i ^ j;
            if (l > i) {
                const h2 a = knn[i], b = knn[l];
                knn[i] = h2min(a, b);
                knn[l] = h2max(a, b);
            }
        }
    }
}

// f32 merge for the once-per-wave lo/hi combine (both sorted asc).
__device__ __forceinline__ void merge16f(float knn[16], const float c[16]) {
#pragma unroll
    for (int i = 0; i < 16; ++i) knn[i] = fminf(knn[i], c[15 - i]);
#pragma unroll
    for (int j = 8; j > 0; j >>= 1) {
#pragma unroll
        for (int i = 0; i < 16; ++i) {
            const int l = i ^ j;
            if (l > i) {
                const float a = knn[i], b = knn[l];
                knn[i] = fminf(a, b);
                knn[l] = fmaxf(a, b);
            }
        }
    }
}

// ---------------------------------------------------------------------------
// Process one 256-j f16-SoA tile (coords stored NEGATED): 8 batches of 32 j.
// unroll 2: two independent batch chains in flight (ILP to cover LDS latency
// and the min/max dependence chain — round-8 residual 23% stall).
// ---------------------------------------------------------------------------
template <bool HAS_SELF>
__device__ __forceinline__ void process_tile(const float4* __restrict__ xs4,
                                             const float4* __restrict__ ys4,
                                             const float4* __restrict__ zs4,
                                             int jg0, int i,
                                             h2 qx, h2 qy, h2 qz,
                                             h2 knn[16]) {
#pragma unroll 2
    for (int bb = 0; bb < TJ / 32; ++bb) {
        h2 c[16];
#pragma unroll
        for (int r = 0; r < 4; ++r) {
            const H2x4 hx = __builtin_bit_cast(H2x4, xs4[bb * 4 + r]); // b128 broadcast
            const H2x4 hy = __builtin_bit_cast(H2x4, ys4[bb * 4 + r]);
            const H2x4 hz = __builtin_bit_cast(H2x4, zs4[bb * 4 + r]);
#pragma unroll
            for (int t = 0; t < 4; ++t) {
                const h2 dx = h2add(qx, hx.v[t]);
                const h2 dy = h2add(qy, hy.v[t]);
                const h2 dz = h2add(qz, hz.v[t]);
                h2 d = h2mul(dx, dx);
                d = h2fma(dy, dy, d);
                d = h2fma(dz, dz, d);
                if (HAS_SELF) {
                    const int j0 = jg0 + bb * 32 + r * 8 + 2 * t;
                    if (j0 == i)     d.x = (__fp16)SENT_F;
                    if (j0 + 1 == i) d.y = (__fp16)SENT_F;
                }
                c[r * 4 + t] = d;
            }
        }
        oems_sort16h(c);
        merge16h(knn, c);
    }
}

// ---------------------------------------------------------------------------
// Kernel 1: per-point mean of 16 smallest non-self squared distances.
// Block = 256 threads = 4 waves (round-8 structure: 44 VGPR, 90 us baseline).
// Global loads for tile t+1 are issued BEFORE processing tile t (software
// prefetch; single LDS buffer is safe — the wave is lockstep, writes happen
// after processing completes).
// ---------------------------------------------------------------------------
__global__ __launch_bounds__(BLK, 4) void knn_kernel(const float* __restrict__ pcs,
                                                     float* __restrict__ knn_out) {
    __shared__ float4 s[JSPLIT][3][TJ / 8];      // f16 SoA x/y/z, 6 KB
    __shared__ float  lst[JSPLIT][PTS][K_ + 1];  // 17.4 KB, +1 pad

    const int b    = blockIdx.x >> 6;            // 64 blocks per batch
    const int grp  = blockIdx.x & 63;
    const int i0   = grp * PTS;
    const int lane = threadIdx.x & 63;
    const int w    = threadIdx.x >> 6;

    const float* __restrict__ src = pcs + (size_t)b * N_ * 3;

    const int i  = i0 + lane;
    const __fp16 qxh = (__fp16)src[3 * i + 0];   // RTN, same grid as candidates
    const __fp16 qyh = (__fp16)src[3 * i + 1];
    const __fp16 qzh = (__fp16)src[3 * i + 2];
    const h2 qx = {qxh, qxh}, qy = {qyh, qyh}, qz = {qzh, qzh};

    const h2 sent = {(__fp16)SENT_F, (__fp16)SENT_F};
    h2 knn[K_];
#pragma unroll
    for (int t = 0; t < K_; ++t) knn[t] = sent;

    const int jbase = w * CHUNK;
    h2* sxw = (h2*)&s[w][0][0];
    h2* syw = (h2*)&s[w][1][0];
    h2* szw = (h2*)&s[w][2][0];

    // prefetch tile 0
    const float4* __restrict__ g4 = (const float4*)(src + (size_t)jbase * 3);
    float4 f0 = g4[3 * lane + 0];
    float4 f1 = g4[3 * lane + 1];
    float4 f2 = g4[3 * lane + 2];

#pragma unroll 1
    for (int t0 = 0; t0 < CHUNK; t0 += TJ) {
        // ---- stage prefetched tile: convert NEGATED (RTN) to f16 pairs
        sxw[2 * lane + 0] = h2{(__fp16)(-f0.x), (__fp16)(-f0.w)};
        sxw[2 * lane + 1] = h2{(__fp16)(-f1.z), (__fp16)(-f2.y)};
        syw[2 * lane + 0] = h2{(__fp16)(-f0.y), (__fp16)(-f1.x)};
        syw[2 * lane + 1] = h2{(__fp16)(-f1.w), (__fp16)(-f2.z)};
        szw[2 * lane + 0] = h2{(__fp16)(-f0.z), (__fp16)(-f1.y)};
        szw[2 * lane + 1] = h2{(__fp16)(-f2.x), (__fp16)(-f2.w)};
        // wave-private quadrant; lanes lockstep within the wave, compiler
        // inserts lgkmcnt waits for the write->read dependence. No barrier.

        // ---- issue next tile's global loads (latency hidden by processing)
        if (t0 + TJ < CHUNK) {
            const float4* __restrict__ gn =
                (const float4*)(src + (size_t)(jbase + t0 + TJ) * 3);
            f0 = gn[3 * lane + 0];
            f1 = gn[3 * lane + 1];
            f2 = gn[3 * lane + 2];
        }

        const int jg0 = jbase + t0;
        if ((i0 >> 8) == (jg0 >> 8)) {
            process_tile<true >(&s[w][0][0], &s[w][1][0], &s[w][2][0],
                                jg0, i, qx, qy, qz, knn);
        } else {
            process_tile<false>(&s[w][0][0], &s[w][1][0], &s[w][2][0],
                                jg0, i, qx, qy, qz, knn);
        }
    }

    // ---- combine the two packed streams (lo/hi), once per wave
    float lo[K_], hi[K_];
#pragma unroll
    for (int t = 0; t < K_; ++t) { lo[t] = (float)knn[t].x; hi[t] = (float)knn[t].y; }
    merge16f(lo, hi);   // lowest 16 of 32, sorted asc

#pragma unroll
    for (int q = 0; q < K_; ++q) lst[w][lane][q] = lo[q];
    lst[w][lane][K_] = SENT_F;
    __syncthreads();

    // ---- 4-way merge of sorted lists, one thread per point (wave 0)
    if (threadIdx.x < PTS) {
        const int l = threadIdx.x;
        int p0 = 0, p1 = 0, p2 = 0, p3 = 0;
        float h0 = lst[0][l][0], h1 = lst[1][l][0];
        float h2v = lst[2][l][0], h3 = lst[3][l][0];
        float sm = 0.0f;
#pragma unroll
        for (int step = 0; step < K_; ++step) {
            const float m = fminf(fminf(h0, h1), fminf(h2v, h3));
            sm += m;
            if (h0 == m)       { h0 = lst[0][l][++p0]; }
            else if (h1 == m)  { h1 = lst[1][l][++p1]; }
            else if (h2v == m) { h2v = lst[2][l][++p2]; }
            else               { h3 = lst[3][l][++p3]; }
        }
        knn_out[b * N_ + i0 + l] = sm * (1.0f / (float)K_);
    }
}

// ---------------------------------------------------------------------------
// Block reduction helper (256 threads = 4 waves)
// ---------------------------------------------------------------------------
__device__ __forceinline__ float block_reduce_sum_256(float v, float* sbuf) {
    const int lane = threadIdx.x & 63;
    const int w    = threadIdx.x >> 6;
#pragma unroll
    for (int o = 32; o > 0; o >>= 1) v += __shfl_down(v, o, 64);
    __syncthreads();
    if (lane == 0) sbuf[w] = v;
    __syncthreads();
    return sbuf[0] + sbuf[1] + sbuf[2] + sbuf[3];
}

// ---------------------------------------------------------------------------
// Kernel 2: per-batch mean, std (two-pass), threshold, penalty partial sum,
// fused final: atomicAdd of scaled penalty into out[0] (memset to 0 first).
// ---------------------------------------------------------------------------
__global__ __launch_bounds__(256) void stats_kernel(const float* __restrict__ knn_d,
                                                    float* __restrict__ out) {
    const int b   = blockIdx.x;
    const int tid = threadIdx.x;
    const float* __restrict__ x = knn_d + (size_t)b * N_;

    __shared__ float sbuf[4];

    float v[16];
    float s = 0.0f;
#pragma unroll
    for (int t = 0; t < 16; ++t) {
        v[t] = x[tid + t * 256];
        s += v[t];
    }
    const float total = block_reduce_sum_256(s, sbuf);
    const float mu = total * (1.0f / (float)N_);

    float vs = 0.0f;
#pragma unroll
    for (int t = 0; t < 16; ++t) {
        const float d = v[t] - mu;
        vs += d * d;
    }
    const float var    = block_reduce_sum_256(vs, sbuf) * (1.0f / (float)N_);
    const float thresh = mu + ALPHA_ * sqrtf(var);

    float p = 0.0f;
#pragma unroll
    for (int t = 0; t < 16; ++t) {
        if (v[t] > thresh) p += v[t];
    }
    const float psum = block_reduce_sum_256(p, sbuf);
    if (tid == 0) atomicAdd(out, psum * (1.0f / (float)(B_ * N_)));
}

extern "C" void kernel_launch(void* const* d_in, const int* in_sizes, int n_in,
                              void* d_out, int out_size, void* d_ws, size_t ws_size,
                              hipStream_t stream) {
    const float* pcs = (const float*)d_in[0];
    float* out = (float*)d_out;

    float* knn_d = (float*)d_ws;             // B*N floats = 256 KB

    (void)hipMemsetAsync(out, 0, sizeof(float), stream);
    knn_kernel<<<B_ * (N_ / PTS), BLK, 0, stream>>>(pcs, knn_d);
    stats_kernel<<<B_, 256, 0, stream>>>(knn_d, out);
}